// Round 15
// baseline (58.802 us; speedup 1.0000x reference)
//
#include <hip/hip_runtime.h>
#include <hip/hip_bf16.h>
#include <stdint.h>

#define H 512
#define W 512
#define HW (H * W)

__device__ __forceinline__ int refl(int i, int n) {
    // BORDER_REFLECT_101: -1 -> 1, n -> n-2
    return i < 0 ? -i : (i >= n ? 2 * n - 2 - i : i);
}

// pack 8 gray bytes (trunc quantize) from 6 float4s into uint2
__device__ __forceinline__ uint2 gray8(float4 ra, float4 rb, float4 ga, float4 gb,
                                       float4 ba, float4 bb) {
    uint32_t t0 = (uint32_t)((0.2989f * ra.x + 0.587f * ga.x + 0.114f * ba.x) * 255.0f);
    uint32_t t1 = (uint32_t)((0.2989f * ra.y + 0.587f * ga.y + 0.114f * ba.y) * 255.0f);
    uint32_t t2 = (uint32_t)((0.2989f * ra.z + 0.587f * ga.z + 0.114f * ba.z) * 255.0f);
    uint32_t t3 = (uint32_t)((0.2989f * ra.w + 0.587f * ga.w + 0.114f * ba.w) * 255.0f);
    uint32_t t4 = (uint32_t)((0.2989f * rb.x + 0.587f * gb.x + 0.114f * bb.x) * 255.0f);
    uint32_t t5 = (uint32_t)((0.2989f * rb.y + 0.587f * gb.y + 0.114f * bb.y) * 255.0f);
    uint32_t t6 = (uint32_t)((0.2989f * rb.z + 0.587f * gb.z + 0.114f * bb.z) * 255.0f);
    uint32_t t7 = (uint32_t)((0.2989f * rb.w + 0.587f * gb.w + 0.114f * bb.w) * 255.0f);
    uint2 o;
    o.x = t0 | (t1 << 8) | (t2 << 16) | (t3 << 24);
    o.y = t4 | (t5 << 8) | (t6 << 16) | (t7 << 24);
    return o;
}

// ---------------- K1: pure gray stream (proven ~19 us) ----------------
// wave = 2 full rows of one source; 12 independent float4 loads -> 2 uint2 stores.
__global__ __launch_bounds__(256) void k_gray(const float* __restrict__ vis,
                                              const float* __restrict__ ir,
                                              uint8_t* __restrict__ qvis,
                                              uint8_t* __restrict__ qir, int B) {
    int lane = threadIdx.x & 63;
    int gwave = blockIdx.x * 4 + (threadIdx.x >> 6);   // [0, 2*B*256)
    int per_src = B * 256;               // 256 row-pairs per image
    int src = gwave >= per_src;
    int rem = src ? gwave - per_src : gwave;
    int b  = rem >> 8;
    int y0 = (rem & 255) * 2;

    const float4* p4 = (const float4*)((src ? ir : vis) + (size_t)b * 3 * HW);
    uint8_t* q = (src ? qir : qvis) + (size_t)b * HW;

    int o0 = y0 * (W / 4) + lane * 2;
    int o1 = o0 + (W / 4);
    float4 r0a = p4[o0],                 r0b = p4[o0 + 1];
    float4 g0a = p4[o0 + HW / 4],        g0b = p4[o0 + 1 + HW / 4];
    float4 b0a = p4[o0 + 2 * (HW / 4)],  b0b = p4[o0 + 1 + 2 * (HW / 4)];
    float4 r1a = p4[o1],                 r1b = p4[o1 + 1];
    float4 g1a = p4[o1 + HW / 4],        g1b = p4[o1 + 1 + HW / 4];
    float4 b1a = p4[o1 + 2 * (HW / 4)],  b1b = p4[o1 + 1 + 2 * (HW / 4)];

    uint2 q0 = gray8(r0a, r0b, g0a, g0b, b0a, b0b);
    uint2 q1 = gray8(r1a, r1b, g1a, g1b, b1a, b1b);
    *(uint2*)(q + (size_t)y0 * W + lane * 8)       = q0;
    *(uint2*)(q + (size_t)(y0 + 1) * W + lane * 8) = q1;
}

// Extract this lane's 10 stencil columns from an 8-byte row segment via shuffles.
__device__ __forceinline__ void row_cols(uint2 v, int lane, float* __restrict__ c) {
    uint32_t lx = __shfl_up(v.y, 1);
    uint32_t rx = __shfl_down(v.x, 1);
    uint32_t lb = (lane == 0)  ? ((v.x >> 8) & 0xffu)  : (lx >> 24);
    uint32_t rb = (lane == 63) ? ((v.y >> 16) & 0xffu) : (rx & 0xffu);
    c[0] = (float)lb;
    c[1] = (float)(v.x & 0xffu);
    c[2] = (float)((v.x >> 8) & 0xffu);
    c[3] = (float)((v.x >> 16) & 0xffu);
    c[4] = (float)(v.x >> 24);
    c[5] = (float)(v.y & 0xffu);
    c[6] = (float)((v.y >> 8) & 0xffu);
    c[7] = (float)((v.y >> 16) & 0xffu);
    c[8] = (float)(v.y >> 24);
    c[9] = (float)rb;
}

__device__ __forceinline__ void sobel_row8(const uint8_t* __restrict__ q, int y, int lane,
                                           float* __restrict__ mag) {
    const uint2* rm = (const uint2*)(q + (size_t)refl(y - 1, H) * W);
    const uint2* r0 = (const uint2*)(q + (size_t)y * W);
    const uint2* rp = (const uint2*)(q + (size_t)refl(y + 1, H) * W);
    uint2 vm = rm[lane], v0 = r0[lane], vp = rp[lane];
    float c0[10], c1[10], c2[10];
    row_cols(vm, lane, c0);
    row_cols(v0, lane, c1);
    row_cols(vp, lane, c2);
    float sx[10], sy[10];
    #pragma unroll
    for (int j = 0; j < 10; ++j) {
        sx[j] = c0[j] + 2.0f * c1[j] + c2[j];
        sy[j] = c2[j] - c0[j];
    }
    #pragma unroll
    for (int k = 0; k < 8; ++k) {
        float gx = sx[k + 2] - sx[k];
        float gy = sy[k] + 2.0f * sy[k + 1] + sy[k + 2];
        mag[k] = sqrtf(gx * gx + gy * gy);
    }
}

// ---------------- K2: per-ROW sobel min/max from q (L2-hot, tiny) ----------------
// one row-task per wave: 3 independent uint2 loads, one sobel, wave-reduce, 8B store.
__global__ __launch_bounds__(256) void k_mm(const uint8_t* __restrict__ qvis,
                                            const uint8_t* __restrict__ qir,
                                            float* __restrict__ pm, int B) {
    int lane = threadIdx.x & 63;
    int nwg = gridDim.x;
    int bid = (blockIdx.x & 7) * (nwg >> 3) + (blockIdx.x >> 3);  // bijective (nwg%8==0)
    int task = bid * 4 + (threadIdx.x >> 6);    // [0, 2*B*H)
    int per_src = B * H;                        // 8192
    int src = task >= per_src;
    int rem = src ? task - per_src : task;
    int b = rem >> 9;
    int y = rem & 511;
    const uint8_t* q = (src ? qir : qvis) + (size_t)b * HW;

    float mag[8];
    sobel_row8(q, y, lane, mag);

    float mn = mag[0], mx = mag[0];
    #pragma unroll
    for (int k = 1; k < 8; ++k) {
        mn = fminf(mn, mag[k]);
        mx = fmaxf(mx, mag[k]);
    }
    #pragma unroll
    for (int o = 32; o > 0; o >>= 1) {
        mn = fminf(mn, __shfl_down(mn, o));
        mx = fmaxf(mx, __shfl_down(mx, o));
    }
    if (lane == 0) {
        float* o = pm + ((size_t)(src * B + b) * H + y) * 2;
        o[0] = mn;
        o[1] = mx;
    }
}

// ---------------- K3: minmax finalize + blend + |diff| (q-based, proven ~10 us) -----
// block = 4 waves; each wave handles rows y0+w and y0+w+4 (8 rows per block).
__global__ __launch_bounds__(256) void k_loss(const float* __restrict__ vis,
                                              const float* __restrict__ ir,
                                              const float* __restrict__ fus,
                                              const uint8_t* __restrict__ qvis,
                                              const uint8_t* __restrict__ qir,
                                              const float* __restrict__ pm,
                                              float* __restrict__ partial, int B) {
    int w = threadIdx.x >> 6, lane = threadIdx.x & 63;
    int b = blockIdx.x >> 6;
    int y0 = (blockIdx.x & 63) * 8;

    __shared__ float sred[4];
    {
        // finalize per-image min/max from 512 per-row partials (8 entries/lane)
        int src = w >> 1, qsel = w & 1;
        const float* base = pm + (size_t)(src * B + b) * H * 2;
        float v = base[lane * 2 + qsel];
        #pragma unroll
        for (int j = 1; j < 8; ++j) {
            float t = base[(lane + j * 64) * 2 + qsel];
            v = qsel ? fmaxf(v, t) : fminf(v, t);
        }
        if (qsel == 0) {
            #pragma unroll
            for (int o = 32; o > 0; o >>= 1) v = fminf(v, __shfl_down(v, o));
        } else {
            #pragma unroll
            for (int o = 32; o > 0; o >>= 1) v = fmaxf(v, __shfl_down(v, o));
        }
        if (lane == 0) sred[w] = v;
    }
    __syncthreads();
    float mn_v = sred[0], mx_v = sred[1], mn_i = sred[2], mx_i = sred[3];
    float inv_v = 1.0f / fmaxf(mx_v - mn_v, 1e-8f);
    float inv_i = 1.0f / fmaxf(mx_i - mn_i, 1e-8f);

    float acc = 0.0f;
    #pragma unroll
    for (int rr = 0; rr < 2; ++rr) {
        int y = y0 + w + rr * 4;
        float mv[8], mi[8];
        sobel_row8(qvis + (size_t)b * HW, y, lane, mv);
        sobel_row8(qir  + (size_t)b * HW, y, lane, mi);

        float wv[8], wi[8];
        #pragma unroll
        for (int k = 0; k < 8; ++k) {
            float sv = (mv[k] - mn_v) * inv_v;
            float si = (mi[k] - mn_i) * inv_i;
            float den = sv + si + 1e-8f;
            float rden = 1.0f / den;
            wv[k] = sv * rden;
            wi[k] = si * rden;
        }

        int i = y * W + lane * 8;
        #pragma unroll
        for (int ch = 0; ch < 3; ++ch) {
            size_t e4 = ((((size_t)b * 3 + ch) * HW) + i) >> 2;
            const float4* v4 = (const float4*)vis;
            const float4* r4 = (const float4*)ir;
            const float4* f4 = (const float4*)fus;
            float4 va = v4[e4], vb = v4[e4 + 1];
            float4 ra = r4[e4], rb = r4[e4 + 1];
            float4 fa = f4[e4], fb = f4[e4 + 1];
            acc += fabsf(wv[0] * va.x + wi[0] * ra.x - fa.x);
            acc += fabsf(wv[1] * va.y + wi[1] * ra.y - fa.y);
            acc += fabsf(wv[2] * va.z + wi[2] * ra.z - fa.z);
            acc += fabsf(wv[3] * va.w + wi[3] * ra.w - fa.w);
            acc += fabsf(wv[4] * vb.x + wi[4] * rb.x - fb.x);
            acc += fabsf(wv[5] * vb.y + wi[5] * rb.y - fb.y);
            acc += fabsf(wv[6] * vb.z + wi[6] * rb.z - fb.z);
            acc += fabsf(wv[7] * vb.w + wi[7] * rb.w - fb.w);
        }
    }

    #pragma unroll
    for (int o = 32; o > 0; o >>= 1) acc += __shfl_down(acc, o);
    __shared__ float ssum[4];
    if (lane == 0) ssum[w] = acc;
    __syncthreads();
    if (threadIdx.x == 0) partial[blockIdx.x] = ssum[0] + ssum[1] + ssum[2] + ssum[3];
}

// ---------------- K4: final reduce ----------------
__global__ void k_final(const float* __restrict__ partial, int n, float* __restrict__ out,
                        long long N) {
    double s = 0.0;
    for (int i = threadIdx.x; i < n; i += 256) s += (double)partial[i];
    __shared__ double sm[256];
    sm[threadIdx.x] = s;
    __syncthreads();
    for (int k = 128; k > 0; k >>= 1) {
        if (threadIdx.x < k) sm[threadIdx.x] += sm[threadIdx.x + k];
        __syncthreads();
    }
    if (threadIdx.x == 0) out[0] = (float)(sm[0] / (double)N);
}

extern "C" void kernel_launch(void* const* d_in, const int* in_sizes, int n_in,
                              void* d_out, int out_size, void* d_ws, size_t ws_size,
                              hipStream_t stream) {
    const float* vis = (const float*)d_in[0];
    const float* ir  = (const float*)d_in[1];
    const float* fus = (const float*)d_in[2];
    int B = in_sizes[0] / (3 * HW);  // 16

    uint8_t* qvis = (uint8_t*)d_ws;
    uint8_t* qir  = qvis + (size_t)B * HW;
    float* pm      = (float*)(qir + (size_t)B * HW);  // 2*B*512*2 floats (128 KB)
    float* partial = pm + (size_t)2 * B * H * 2;      // 1024 floats
    float* out = (float*)d_out;

    int nblk_gray = 2 * B * 256 / 4;    // 2048 blocks x 4 waves, 2 rows/wave
    k_gray<<<nblk_gray, 256, 0, stream>>>(vis, ir, qvis, qir, B);

    int nblk_mm = 2 * B * H / 4;        // 4096 blocks x 4 waves, 1 row/wave
    k_mm<<<nblk_mm, 256, 0, stream>>>(qvis, qir, pm, B);

    int nblk_loss = B * (H / 8);        // 1024 blocks
    k_loss<<<nblk_loss, 256, 0, stream>>>(vis, ir, fus, qvis, qir, pm, partial, B);

    k_final<<<1, 256, 0, stream>>>(partial, nblk_loss, out, (long long)B * 3 * HW);
}

// Round 16
// 50.635 us; speedup vs baseline: 1.1613x; 1.1613x over previous
//
#include <hip/hip_runtime.h>
#include <hip/hip_bf16.h>
#include <stdint.h>

#define H 512
#define W 512
#define HW (H * W)

typedef float f32x4 __attribute__((ext_vector_type(4)));

__device__ __forceinline__ int refl(int i, int n) {
    // BORDER_REFLECT_101: -1 -> 1, n -> n-2
    return i < 0 ? -i : (i >= n ? 2 * n - 2 - i : i);
}

// Inline-asm 16B load: compiler cannot narrow it or sink it into a serial
// load->use round (the VGPR=32 re-serialization that capped every gray pass).
__device__ __forceinline__ f32x4 gload4(const f32x4* p) {
    f32x4 d;
    asm volatile("global_load_dwordx4 %0, %1, off" : "=v"(d) : "v"(p) : "memory");
    return d;
}

// quantized gray (floor == uint8 trunc for [0,255]) for 8 px from 6 f32x4s
// (L[0],L[1]=R; L[2],L[3]=G; L[4],L[5]=B). Bit-identical expression in both passes.
__device__ __forceinline__ void gray8x(const f32x4* __restrict__ L, float* __restrict__ g) {
    g[0] = floorf((0.2989f * L[0].x + 0.587f * L[2].x + 0.114f * L[4].x) * 255.0f);
    g[1] = floorf((0.2989f * L[0].y + 0.587f * L[2].y + 0.114f * L[4].y) * 255.0f);
    g[2] = floorf((0.2989f * L[0].z + 0.587f * L[2].z + 0.114f * L[4].z) * 255.0f);
    g[3] = floorf((0.2989f * L[0].w + 0.587f * L[2].w + 0.114f * L[4].w) * 255.0f);
    g[4] = floorf((0.2989f * L[1].x + 0.587f * L[3].x + 0.114f * L[5].x) * 255.0f);
    g[5] = floorf((0.2989f * L[1].y + 0.587f * L[3].y + 0.114f * L[5].y) * 255.0f);
    g[6] = floorf((0.2989f * L[1].z + 0.587f * L[3].z + 0.114f * L[5].z) * 255.0f);
    g[7] = floorf((0.2989f * L[1].w + 0.587f * L[3].w + 0.114f * L[5].w) * 255.0f);
}

// float4-based variant for k_loss (kept identical in FP expression)
__device__ __forceinline__ void gray8f(float4 ra, float4 rb, float4 ga, float4 gb,
                                       float4 ba, float4 bb, float* __restrict__ g) {
    g[0] = floorf((0.2989f * ra.x + 0.587f * ga.x + 0.114f * ba.x) * 255.0f);
    g[1] = floorf((0.2989f * ra.y + 0.587f * ga.y + 0.114f * ba.y) * 255.0f);
    g[2] = floorf((0.2989f * ra.z + 0.587f * ga.z + 0.114f * ba.z) * 255.0f);
    g[3] = floorf((0.2989f * ra.w + 0.587f * ga.w + 0.114f * ba.w) * 255.0f);
    g[4] = floorf((0.2989f * rb.x + 0.587f * gb.x + 0.114f * bb.x) * 255.0f);
    g[5] = floorf((0.2989f * rb.y + 0.587f * gb.y + 0.114f * bb.y) * 255.0f);
    g[6] = floorf((0.2989f * rb.z + 0.587f * gb.z + 0.114f * bb.z) * 255.0f);
    g[7] = floorf((0.2989f * rb.w + 0.587f * gb.w + 0.114f * bb.w) * 255.0f);
}

__device__ __forceinline__ void grayrow(const float4* __restrict__ p4, int row, int lane,
                                        float* __restrict__ g) {
    int o = row * (W / 4) + lane * 2;
    float4 ra = p4[o],                 rb = p4[o + 1];
    float4 ga = p4[o + HW / 4],        gb = p4[o + 1 + HW / 4];
    float4 ba = p4[o + 2 * (HW / 4)],  bb = p4[o + 1 + 2 * (HW / 4)];
    gray8f(ra, rb, ga, gb, ba, bb, g);
}

// 10-col halo-extended window from this lane's 8 gray px via shuffles.
__device__ __forceinline__ void win10(const float* __restrict__ g, int lane,
                                      float* __restrict__ h) {
    #pragma unroll
    for (int j = 0; j < 8; ++j) h[j + 1] = g[j];
    float up = __shfl_up(g[7], 1);
    float dn = __shfl_down(g[0], 1);
    h[0] = (lane == 0)  ? g[1] : up;   // x=-1  -> x=1
    h[9] = (lane == 63) ? g[6] : dn;   // x=512 -> x=510
}

__device__ __forceinline__ void sobel8(const float* __restrict__ hm,
                                       const float* __restrict__ h0,
                                       const float* __restrict__ hp,
                                       float* __restrict__ mag) {
    float sx[10], sy[10];
    #pragma unroll
    for (int j = 0; j < 10; ++j) {
        sx[j] = hm[j] + 2.0f * h0[j] + hp[j];
        sy[j] = hp[j] - hm[j];
    }
    #pragma unroll
    for (int k = 0; k < 8; ++k) {
        float gx = sx[k + 2] - sx[k];
        float gy = sy[k] + 2.0f * sy[k + 1] + sy[k + 2];
        mag[k] = sqrtf(gx * gx + gy * gy);
    }
}

// ---------------- K1: per-ROW sobel min/max from RGB, inline-asm load batch ---------
// ONE row-task per wave; ALL 18 float4 loads issued back-to-back via asm, one
// vmcnt(0), then consume. MLP = 18/wave by construction.
__global__ __launch_bounds__(256) void k_mm(const float* __restrict__ vis,
                                            const float* __restrict__ ir,
                                            float* __restrict__ pm, int B) {
    int lane = threadIdx.x & 63;
    int nwg = gridDim.x;
    int bid = (blockIdx.x & 7) * (nwg >> 3) + (blockIdx.x >> 3);  // bijective (nwg%8==0)
    int task = bid * 4 + (threadIdx.x >> 6);    // [0, 2*B*H)
    int per_src = B * H;                        // 8192
    int src = task >= per_src;
    int rem = src ? task - per_src : task;
    int b = rem >> 9;
    int y = rem & 511;
    const f32x4* p4 = (const f32x4*)((src ? ir : vis) + (size_t)b * 3 * HW);

    int om = refl(y - 1, H) * (W / 4) + lane * 2;
    int o0 = y * (W / 4) + lane * 2;
    int op = refl(y + 1, H) * (W / 4) + lane * 2;

    f32x4 L[18];
    // row y-1: R,R+1, G,G+1, B,B+1
    L[0]  = gload4(p4 + om);
    L[1]  = gload4(p4 + om + 1);
    L[2]  = gload4(p4 + om + HW / 4);
    L[3]  = gload4(p4 + om + 1 + HW / 4);
    L[4]  = gload4(p4 + om + 2 * (HW / 4));
    L[5]  = gload4(p4 + om + 1 + 2 * (HW / 4));
    // row y
    L[6]  = gload4(p4 + o0);
    L[7]  = gload4(p4 + o0 + 1);
    L[8]  = gload4(p4 + o0 + HW / 4);
    L[9]  = gload4(p4 + o0 + 1 + HW / 4);
    L[10] = gload4(p4 + o0 + 2 * (HW / 4));
    L[11] = gload4(p4 + o0 + 1 + 2 * (HW / 4));
    // row y+1
    L[12] = gload4(p4 + op);
    L[13] = gload4(p4 + op + 1);
    L[14] = gload4(p4 + op + HW / 4);
    L[15] = gload4(p4 + op + 1 + HW / 4);
    L[16] = gload4(p4 + op + 2 * (HW / 4));
    L[17] = gload4(p4 + op + 1 + 2 * (HW / 4));
    asm volatile("s_waitcnt vmcnt(0)" ::: "memory");
    __builtin_amdgcn_sched_barrier(0);   // rule #18: keep consumers below the wait

    float gm[8], g0[8], gp[8];
    gray8x(&L[0],  gm);
    gray8x(&L[6],  g0);
    gray8x(&L[12], gp);
    float hm[10], h0[10], hp[10];
    win10(gm, lane, hm);
    win10(g0, lane, h0);
    win10(gp, lane, hp);
    float mag[8];
    sobel8(hm, h0, hp, mag);

    float mn = mag[0], mx = mag[0];
    #pragma unroll
    for (int k = 1; k < 8; ++k) {
        mn = fminf(mn, mag[k]);
        mx = fmaxf(mx, mag[k]);
    }
    #pragma unroll
    for (int o = 32; o > 0; o >>= 1) {
        mn = fminf(mn, __shfl_down(mn, o));
        mx = fmaxf(mx, __shfl_down(mx, o));
    }
    if (lane == 0) {
        float* o = pm + ((size_t)(src * B + b) * H + y) * 2;
        o[0] = mn;
        o[1] = mx;
    }
}

// |blend - fusion| for 8 px of one channel (a = px0-3, b = px4-7)
__device__ __forceinline__ float acc8(const float* __restrict__ wv,
                                      const float* __restrict__ wi,
                                      float4 va, float4 vb, float4 ra, float4 rb,
                                      float4 fa, float4 fb) {
    float s = 0.0f;
    s += fabsf(wv[0] * va.x + wi[0] * ra.x - fa.x);
    s += fabsf(wv[1] * va.y + wi[1] * ra.y - fa.y);
    s += fabsf(wv[2] * va.z + wi[2] * ra.z - fa.z);
    s += fabsf(wv[3] * va.w + wi[3] * ra.w - fa.w);
    s += fabsf(wv[4] * vb.x + wi[4] * rb.x - fb.x);
    s += fabsf(wv[5] * vb.y + wi[5] * rb.y - fb.y);
    s += fabsf(wv[6] * vb.z + wi[6] * rb.z - fb.z);
    s += fabsf(wv[7] * vb.w + wi[7] * rb.w - fb.w);
    return s;
}

// ---------------- K2: minmax finalize + blend + |diff| (gray recomputed, no q) ------
// one wave per image row: 42 independent float4 loads; center-row RGB doubles as
// blend input. Block = 4 waves = 4 consecutive rows. (r14's proven-fast kernel.)
__global__ __launch_bounds__(256) void k_loss(const float* __restrict__ vis,
                                              const float* __restrict__ ir,
                                              const float* __restrict__ fus,
                                              const float* __restrict__ pm,
                                              float* __restrict__ partial, int B) {
    int w = threadIdx.x >> 6, lane = threadIdx.x & 63;
    int nwg = gridDim.x;
    int bid = (blockIdx.x & 7) * (nwg >> 3) + (blockIdx.x >> 3);  // bijective (nwg%8==0)
    int b = bid >> 7;
    int y = (bid & 127) * 4 + w;

    __shared__ float sred[4];
    {
        // finalize per-image min/max from 512 per-row partials (8 entries/lane)
        int src = w >> 1, qsel = w & 1;
        const float* base = pm + (size_t)(src * B + b) * H * 2;
        float v = base[lane * 2 + qsel];
        #pragma unroll
        for (int j = 1; j < 8; ++j) {
            float t = base[(lane + j * 64) * 2 + qsel];
            v = qsel ? fmaxf(v, t) : fminf(v, t);
        }
        if (qsel == 0) {
            #pragma unroll
            for (int o = 32; o > 0; o >>= 1) v = fminf(v, __shfl_down(v, o));
        } else {
            #pragma unroll
            for (int o = 32; o > 0; o >>= 1) v = fmaxf(v, __shfl_down(v, o));
        }
        if (lane == 0) sred[w] = v;
    }
    __syncthreads();
    float mn_v = sred[0], mx_v = sred[1], mn_i = sred[2], mx_i = sred[3];
    float inv_v = 1.0f / fmaxf(mx_v - mn_v, 1e-8f);
    float inv_i = 1.0f / fmaxf(mx_i - mn_i, 1e-8f);

    const float4* pv = (const float4*)(vis + (size_t)b * 3 * HW);
    const float4* pi = (const float4*)(ir  + (size_t)b * 3 * HW);
    const float4* pf = (const float4*)(fus + (size_t)b * 3 * HW);

    int o = y * (W / 4) + lane * 2;
    float4 vra = pv[o],                 vrb = pv[o + 1];
    float4 vga = pv[o + HW / 4],        vgb = pv[o + 1 + HW / 4];
    float4 vba = pv[o + 2 * (HW / 4)],  vbb = pv[o + 1 + 2 * (HW / 4)];
    float4 ira = pi[o],                 irb = pi[o + 1];
    float4 iga = pi[o + HW / 4],        igb = pi[o + 1 + HW / 4];
    float4 iba = pi[o + 2 * (HW / 4)],  ibb = pi[o + 1 + 2 * (HW / 4)];
    float4 fra = pf[o],                 frb = pf[o + 1];
    float4 fga = pf[o + HW / 4],        fgb = pf[o + 1 + HW / 4];
    float4 fba = pf[o + 2 * (HW / 4)],  fbb = pf[o + 1 + 2 * (HW / 4)];

    float mv[8], mi[8];
    {
        float g0[8], gm[8], gp[8];
        gray8f(vra, vrb, vga, vgb, vba, vbb, g0);
        grayrow(pv, refl(y - 1, H), lane, gm);
        grayrow(pv, refl(y + 1, H), lane, gp);
        float hm[10], h0[10], hp[10];
        win10(gm, lane, hm); win10(g0, lane, h0); win10(gp, lane, hp);
        sobel8(hm, h0, hp, mv);
    }
    {
        float g0[8], gm[8], gp[8];
        gray8f(ira, irb, iga, igb, iba, ibb, g0);
        grayrow(pi, refl(y - 1, H), lane, gm);
        grayrow(pi, refl(y + 1, H), lane, gp);
        float hm[10], h0[10], hp[10];
        win10(gm, lane, hm); win10(g0, lane, h0); win10(gp, lane, hp);
        sobel8(hm, h0, hp, mi);
    }

    float wv[8], wi[8];
    #pragma unroll
    for (int k = 0; k < 8; ++k) {
        float sv = (mv[k] - mn_v) * inv_v;
        float si = (mi[k] - mn_i) * inv_i;
        float den = sv + si + 1e-8f;
        float rden = 1.0f / den;
        wv[k] = sv * rden;
        wi[k] = si * rden;
    }

    float acc = 0.0f;
    acc += acc8(wv, wi, vra, vrb, ira, irb, fra, frb);
    acc += acc8(wv, wi, vga, vgb, iga, igb, fga, fgb);
    acc += acc8(wv, wi, vba, vbb, iba, ibb, fba, fbb);

    #pragma unroll
    for (int o2 = 32; o2 > 0; o2 >>= 1) acc += __shfl_down(acc, o2);
    __shared__ float ssum[4];
    if (lane == 0) ssum[w] = acc;
    __syncthreads();
    if (threadIdx.x == 0) partial[blockIdx.x] = ssum[0] + ssum[1] + ssum[2] + ssum[3];
}

// ---------------- K3: final reduce ----------------
__global__ void k_final(const float* __restrict__ partial, int n, float* __restrict__ out,
                        long long N) {
    double s = 0.0;
    for (int i = threadIdx.x; i < n; i += 256) s += (double)partial[i];
    __shared__ double sm[256];
    sm[threadIdx.x] = s;
    __syncthreads();
    for (int k = 128; k > 0; k >>= 1) {
        if (threadIdx.x < k) sm[threadIdx.x] += sm[threadIdx.x + k];
        __syncthreads();
    }
    if (threadIdx.x == 0) out[0] = (float)(sm[0] / (double)N);
}

extern "C" void kernel_launch(void* const* d_in, const int* in_sizes, int n_in,
                              void* d_out, int out_size, void* d_ws, size_t ws_size,
                              hipStream_t stream) {
    const float* vis = (const float*)d_in[0];
    const float* ir  = (const float*)d_in[1];
    const float* fus = (const float*)d_in[2];
    int B = in_sizes[0] / (3 * HW);  // 16

    float* pm      = (float*)d_ws;                   // 2*B*512*2 floats (512 KB)
    float* partial = pm + (size_t)2 * B * H * 2;     // 2048 floats
    float* out = (float*)d_out;

    int nblk_mm = 2 * B * H / 4;        // 4096 blocks x 4 waves, 1 row-task/wave
    k_mm<<<nblk_mm, 256, 0, stream>>>(vis, ir, pm, B);

    int nblk_loss = B * H / 4;          // 2048 blocks x 4 waves (nwg%8==0)
    k_loss<<<nblk_loss, 256, 0, stream>>>(vis, ir, fus, pm, partial, B);

    k_final<<<1, 256, 0, stream>>>(partial, nblk_loss, out, (long long)B * 3 * HW);
}

// Round 17
// 50.513 us; speedup vs baseline: 1.1641x; 1.0024x over previous
//
#include <hip/hip_runtime.h>
#include <hip/hip_bf16.h>
#include <stdint.h>

#define H 512
#define W 512
#define HW (H * W)

typedef float f32x4 __attribute__((ext_vector_type(4)));

__device__ __forceinline__ int refl(int i, int n) {
    // BORDER_REFLECT_101: -1 -> 1, n -> n-2
    return i < 0 ? -i : (i >= n ? 2 * n - 2 - i : i);
}

// Inline-asm 16B load: compiler cannot narrow it or sink it into a serial
// load->use round.
__device__ __forceinline__ f32x4 gload4(const f32x4* p) {
    f32x4 d;
    asm volatile("global_load_dwordx4 %0, %1, off" : "=v"(d) : "v"(p) : "memory");
    return d;
}

// quantized gray (floor == uint8 trunc for [0,255]) for 8 px from 6 f32x4s
// (L[0],L[1]=R; L[2],L[3]=G; L[4],L[5]=B). Bit-identical expression in both passes.
__device__ __forceinline__ void gray8x(const f32x4* __restrict__ L, float* __restrict__ g) {
    g[0] = floorf((0.2989f * L[0].x + 0.587f * L[2].x + 0.114f * L[4].x) * 255.0f);
    g[1] = floorf((0.2989f * L[0].y + 0.587f * L[2].y + 0.114f * L[4].y) * 255.0f);
    g[2] = floorf((0.2989f * L[0].z + 0.587f * L[2].z + 0.114f * L[4].z) * 255.0f);
    g[3] = floorf((0.2989f * L[0].w + 0.587f * L[2].w + 0.114f * L[4].w) * 255.0f);
    g[4] = floorf((0.2989f * L[1].x + 0.587f * L[3].x + 0.114f * L[5].x) * 255.0f);
    g[5] = floorf((0.2989f * L[1].y + 0.587f * L[3].y + 0.114f * L[5].y) * 255.0f);
    g[6] = floorf((0.2989f * L[1].z + 0.587f * L[3].z + 0.114f * L[5].z) * 255.0f);
    g[7] = floorf((0.2989f * L[1].w + 0.587f * L[3].w + 0.114f * L[5].w) * 255.0f);
}

// float4-based variant for k_loss (kept identical in FP expression)
__device__ __forceinline__ void gray8f(float4 ra, float4 rb, float4 ga, float4 gb,
                                       float4 ba, float4 bb, float* __restrict__ g) {
    g[0] = floorf((0.2989f * ra.x + 0.587f * ga.x + 0.114f * ba.x) * 255.0f);
    g[1] = floorf((0.2989f * ra.y + 0.587f * ga.y + 0.114f * ba.y) * 255.0f);
    g[2] = floorf((0.2989f * ra.z + 0.587f * ga.z + 0.114f * ba.z) * 255.0f);
    g[3] = floorf((0.2989f * ra.w + 0.587f * ga.w + 0.114f * ba.w) * 255.0f);
    g[4] = floorf((0.2989f * rb.x + 0.587f * gb.x + 0.114f * bb.x) * 255.0f);
    g[5] = floorf((0.2989f * rb.y + 0.587f * gb.y + 0.114f * bb.y) * 255.0f);
    g[6] = floorf((0.2989f * rb.z + 0.587f * gb.z + 0.114f * bb.z) * 255.0f);
    g[7] = floorf((0.2989f * rb.w + 0.587f * gb.w + 0.114f * bb.w) * 255.0f);
}

__device__ __forceinline__ void grayrow(const float4* __restrict__ p4, int row, int lane,
                                        float* __restrict__ g) {
    int o = row * (W / 4) + lane * 2;
    float4 ra = p4[o],                 rb = p4[o + 1];
    float4 ga = p4[o + HW / 4],        gb = p4[o + 1 + HW / 4];
    float4 ba = p4[o + 2 * (HW / 4)],  bb = p4[o + 1 + 2 * (HW / 4)];
    gray8f(ra, rb, ga, gb, ba, bb, g);
}

// 10-col halo-extended window from this lane's 8 gray px via shuffles.
__device__ __forceinline__ void win10(const float* __restrict__ g, int lane,
                                      float* __restrict__ h) {
    #pragma unroll
    for (int j = 0; j < 8; ++j) h[j + 1] = g[j];
    float up = __shfl_up(g[7], 1);
    float dn = __shfl_down(g[0], 1);
    h[0] = (lane == 0)  ? g[1] : up;   // x=-1  -> x=1
    h[9] = (lane == 63) ? g[6] : dn;   // x=512 -> x=510
}

__device__ __forceinline__ void sobel8(const float* __restrict__ hm,
                                       const float* __restrict__ h0,
                                       const float* __restrict__ hp,
                                       float* __restrict__ mag) {
    float sx[10], sy[10];
    #pragma unroll
    for (int j = 0; j < 10; ++j) {
        sx[j] = hm[j] + 2.0f * h0[j] + hp[j];
        sy[j] = hp[j] - hm[j];
    }
    #pragma unroll
    for (int k = 0; k < 8; ++k) {
        float gx = sx[k + 2] - sx[k];
        float gy = sy[k] + 2.0f * sy[k + 1] + sy[k + 2];
        mag[k] = sqrtf(gx * gx + gy * gy);
    }
}

// ---------------- K1: per-ROW sobel min/max from RGB, inline-asm load batch ---------
// ONE row-task per wave; ALL 18 float4 loads issued back-to-back via asm, one
// vmcnt(0), then consume. __launch_bounds__(256, 2): 2 waves/EU -> 256-VGPR
// budget so the 72-VGPR load batch LIVES IN REGISTERS (r16's (256) default
// capped the allocator at 40 VGPR and spilled L[] to scratch).
__global__ __launch_bounds__(256, 2) void k_mm(const float* __restrict__ vis,
                                               const float* __restrict__ ir,
                                               float* __restrict__ pm, int B) {
    int lane = threadIdx.x & 63;
    int nwg = gridDim.x;
    int bid = (blockIdx.x & 7) * (nwg >> 3) + (blockIdx.x >> 3);  // bijective (nwg%8==0)
    int task = bid * 4 + (threadIdx.x >> 6);    // [0, 2*B*H)
    int per_src = B * H;                        // 8192
    int src = task >= per_src;
    int rem = src ? task - per_src : task;
    int b = rem >> 9;
    int y = rem & 511;
    const f32x4* p4 = (const f32x4*)((src ? ir : vis) + (size_t)b * 3 * HW);

    int om = refl(y - 1, H) * (W / 4) + lane * 2;
    int o0 = y * (W / 4) + lane * 2;
    int op = refl(y + 1, H) * (W / 4) + lane * 2;

    f32x4 L[18];
    // row y-1: R,R+1, G,G+1, B,B+1
    L[0]  = gload4(p4 + om);
    L[1]  = gload4(p4 + om + 1);
    L[2]  = gload4(p4 + om + HW / 4);
    L[3]  = gload4(p4 + om + 1 + HW / 4);
    L[4]  = gload4(p4 + om + 2 * (HW / 4));
    L[5]  = gload4(p4 + om + 1 + 2 * (HW / 4));
    // row y
    L[6]  = gload4(p4 + o0);
    L[7]  = gload4(p4 + o0 + 1);
    L[8]  = gload4(p4 + o0 + HW / 4);
    L[9]  = gload4(p4 + o0 + 1 + HW / 4);
    L[10] = gload4(p4 + o0 + 2 * (HW / 4));
    L[11] = gload4(p4 + o0 + 1 + 2 * (HW / 4));
    // row y+1
    L[12] = gload4(p4 + op);
    L[13] = gload4(p4 + op + 1);
    L[14] = gload4(p4 + op + HW / 4);
    L[15] = gload4(p4 + op + 1 + HW / 4);
    L[16] = gload4(p4 + op + 2 * (HW / 4));
    L[17] = gload4(p4 + op + 1 + 2 * (HW / 4));
    asm volatile("s_waitcnt vmcnt(0)" ::: "memory");
    __builtin_amdgcn_sched_barrier(0);   // rule #18: keep consumers below the wait

    float gm[8], g0[8], gp[8];
    gray8x(&L[0],  gm);
    gray8x(&L[6],  g0);
    gray8x(&L[12], gp);
    float hm[10], h0[10], hp[10];
    win10(gm, lane, hm);
    win10(g0, lane, h0);
    win10(gp, lane, hp);
    float mag[8];
    sobel8(hm, h0, hp, mag);

    float mn = mag[0], mx = mag[0];
    #pragma unroll
    for (int k = 1; k < 8; ++k) {
        mn = fminf(mn, mag[k]);
        mx = fmaxf(mx, mag[k]);
    }
    #pragma unroll
    for (int o = 32; o > 0; o >>= 1) {
        mn = fminf(mn, __shfl_down(mn, o));
        mx = fmaxf(mx, __shfl_down(mx, o));
    }
    if (lane == 0) {
        float* o = pm + ((size_t)(src * B + b) * H + y) * 2;
        o[0] = mn;
        o[1] = mx;
    }
}

// |blend - fusion| for 8 px of one channel (a = px0-3, b = px4-7)
__device__ __forceinline__ float acc8(const float* __restrict__ wv,
                                      const float* __restrict__ wi,
                                      float4 va, float4 vb, float4 ra, float4 rb,
                                      float4 fa, float4 fb) {
    float s = 0.0f;
    s += fabsf(wv[0] * va.x + wi[0] * ra.x - fa.x);
    s += fabsf(wv[1] * va.y + wi[1] * ra.y - fa.y);
    s += fabsf(wv[2] * va.z + wi[2] * ra.z - fa.z);
    s += fabsf(wv[3] * va.w + wi[3] * ra.w - fa.w);
    s += fabsf(wv[4] * vb.x + wi[4] * rb.x - fb.x);
    s += fabsf(wv[5] * vb.y + wi[5] * rb.y - fb.y);
    s += fabsf(wv[6] * vb.z + wi[6] * rb.z - fb.z);
    s += fabsf(wv[7] * vb.w + wi[7] * rb.w - fb.w);
    return s;
}

// ---------------- K2: minmax finalize + blend + |diff| (gray recomputed, no q) ------
// one wave per image row: 42 independent float4 loads; center-row RGB doubles as
// blend input. Block = 4 waves = 4 consecutive rows. (proven-fast kernel.)
__global__ __launch_bounds__(256) void k_loss(const float* __restrict__ vis,
                                              const float* __restrict__ ir,
                                              const float* __restrict__ fus,
                                              const float* __restrict__ pm,
                                              float* __restrict__ partial, int B) {
    int w = threadIdx.x >> 6, lane = threadIdx.x & 63;
    int nwg = gridDim.x;
    int bid = (blockIdx.x & 7) * (nwg >> 3) + (blockIdx.x >> 3);  // bijective (nwg%8==0)
    int b = bid >> 7;
    int y = (bid & 127) * 4 + w;

    __shared__ float sred[4];
    {
        // finalize per-image min/max from 512 per-row partials (8 entries/lane)
        int src = w >> 1, qsel = w & 1;
        const float* base = pm + (size_t)(src * B + b) * H * 2;
        float v = base[lane * 2 + qsel];
        #pragma unroll
        for (int j = 1; j < 8; ++j) {
            float t = base[(lane + j * 64) * 2 + qsel];
            v = qsel ? fmaxf(v, t) : fminf(v, t);
        }
        if (qsel == 0) {
            #pragma unroll
            for (int o = 32; o > 0; o >>= 1) v = fminf(v, __shfl_down(v, o));
        } else {
            #pragma unroll
            for (int o = 32; o > 0; o >>= 1) v = fmaxf(v, __shfl_down(v, o));
        }
        if (lane == 0) sred[w] = v;
    }
    __syncthreads();
    float mn_v = sred[0], mx_v = sred[1], mn_i = sred[2], mx_i = sred[3];
    float inv_v = 1.0f / fmaxf(mx_v - mn_v, 1e-8f);
    float inv_i = 1.0f / fmaxf(mx_i - mn_i, 1e-8f);

    const float4* pv = (const float4*)(vis + (size_t)b * 3 * HW);
    const float4* pi = (const float4*)(ir  + (size_t)b * 3 * HW);
    const float4* pf = (const float4*)(fus + (size_t)b * 3 * HW);

    int o = y * (W / 4) + lane * 2;
    float4 vra = pv[o],                 vrb = pv[o + 1];
    float4 vga = pv[o + HW / 4],        vgb = pv[o + 1 + HW / 4];
    float4 vba = pv[o + 2 * (HW / 4)],  vbb = pv[o + 1 + 2 * (HW / 4)];
    float4 ira = pi[o],                 irb = pi[o + 1];
    float4 iga = pi[o + HW / 4],        igb = pi[o + 1 + HW / 4];
    float4 iba = pi[o + 2 * (HW / 4)],  ibb = pi[o + 1 + 2 * (HW / 4)];
    float4 fra = pf[o],                 frb = pf[o + 1];
    float4 fga = pf[o + HW / 4],        fgb = pf[o + 1 + HW / 4];
    float4 fba = pf[o + 2 * (HW / 4)],  fbb = pf[o + 1 + 2 * (HW / 4)];

    float mv[8], mi[8];
    {
        float g0[8], gm[8], gp[8];
        gray8f(vra, vrb, vga, vgb, vba, vbb, g0);
        grayrow(pv, refl(y - 1, H), lane, gm);
        grayrow(pv, refl(y + 1, H), lane, gp);
        float hm[10], h0[10], hp[10];
        win10(gm, lane, hm); win10(g0, lane, h0); win10(gp, lane, hp);
        sobel8(hm, h0, hp, mv);
    }
    {
        float g0[8], gm[8], gp[8];
        gray8f(ira, irb, iga, igb, iba, ibb, g0);
        grayrow(pi, refl(y - 1, H), lane, gm);
        grayrow(pi, refl(y + 1, H), lane, gp);
        float hm[10], h0[10], hp[10];
        win10(gm, lane, hm); win10(g0, lane, h0); win10(gp, lane, hp);
        sobel8(hm, h0, hp, mi);
    }

    float wv[8], wi[8];
    #pragma unroll
    for (int k = 0; k < 8; ++k) {
        float sv = (mv[k] - mn_v) * inv_v;
        float si = (mi[k] - mn_i) * inv_i;
        float den = sv + si + 1e-8f;
        float rden = 1.0f / den;
        wv[k] = sv * rden;
        wi[k] = si * rden;
    }

    float acc = 0.0f;
    acc += acc8(wv, wi, vra, vrb, ira, irb, fra, frb);
    acc += acc8(wv, wi, vga, vgb, iga, igb, fga, fgb);
    acc += acc8(wv, wi, vba, vbb, iba, ibb, fba, fbb);

    #pragma unroll
    for (int o2 = 32; o2 > 0; o2 >>= 1) acc += __shfl_down(acc, o2);
    __shared__ float ssum[4];
    if (lane == 0) ssum[w] = acc;
    __syncthreads();
    if (threadIdx.x == 0) partial[blockIdx.x] = ssum[0] + ssum[1] + ssum[2] + ssum[3];
}

// ---------------- K3: final reduce ----------------
__global__ void k_final(const float* __restrict__ partial, int n, float* __restrict__ out,
                        long long N) {
    double s = 0.0;
    for (int i = threadIdx.x; i < n; i += 256) s += (double)partial[i];
    __shared__ double sm[256];
    sm[threadIdx.x] = s;
    __syncthreads();
    for (int k = 128; k > 0; k >>= 1) {
        if (threadIdx.x < k) sm[threadIdx.x] += sm[threadIdx.x + k];
        __syncthreads();
    }
    if (threadIdx.x == 0) out[0] = (float)(sm[0] / (double)N);
}

extern "C" void kernel_launch(void* const* d_in, const int* in_sizes, int n_in,
                              void* d_out, int out_size, void* d_ws, size_t ws_size,
                              hipStream_t stream) {
    const float* vis = (const float*)d_in[0];
    const float* ir  = (const float*)d_in[1];
    const float* fus = (const float*)d_in[2];
    int B = in_sizes[0] / (3 * HW);  // 16

    float* pm      = (float*)d_ws;                   // 2*B*512*2 floats (512 KB)
    float* partial = pm + (size_t)2 * B * H * 2;     // 2048 floats
    float* out = (float*)d_out;

    int nblk_mm = 2 * B * H / 4;        // 4096 blocks x 4 waves, 1 row-task/wave
    k_mm<<<nblk_mm, 256, 0, stream>>>(vis, ir, pm, B);

    int nblk_loss = B * H / 4;          // 2048 blocks x 4 waves (nwg%8==0)
    k_loss<<<nblk_loss, 256, 0, stream>>>(vis, ir, fus, pm, partial, B);

    k_final<<<1, 256, 0, stream>>>(partial, nblk_loss, out, (long long)B * 3 * HW);
}